// Round 13
// baseline (156.589 us; speedup 1.0000x reference)
//
#include <hip/hip_runtime.h>

// HarmonicConvolutionFilter on MI355X (round 13 — A/B DIAGNOSTIC of round-11 body).
// x: [B=4, S=1024, F=512, C=4] f32;  W: [5, K=4, C=4, O=4] f32;  out: [B,S,F,4] f32
//
// Round-10 (rep x4 of round-6 body): dispatch 85us -> T ~= 21.3us, VALUBusy
// 45.9%, FETCH 16.5MB (x L3-resident), occupancy 26.8% -> ~55% dep stalls.
// Round-11 fix (hoist all unconditional gathers; fuse tap loops across
// harmonic pairs; reuse m=1 slice; wave-aligned m3/m4) never ran (3 timeouts).
// dur_us channel noise (harness overhead drifts 52-64us across sessions)
// exceeds the predicted 4-6us effect, so this round submits the round-11
// body in the SAME NREP=4 harness as round 10: direct dispatch-vs-85us A/B.
//   confirmed: dispatch 60-68us (T 15-17us), VALUBusy ~55-65%
//   falsified: dispatch >= 80us -> next round ablates stage vs compute.

#define TS    2
#define NTAP  5
#define FB    512
#define SB    1024
#define BB    4
#define NROW  (TS + 4)
#define ROWP  544
#define NREP  4

typedef float vfloat4 __attribute__((ext_vector_type(4)));

__device__ __forceinline__ void nt_store4(float4 v, float4* p) {
    vfloat4 raw = { v.x, v.y, v.z, v.w };
    __builtin_nontemporal_store(raw, (vfloat4*)p);
}

__device__ __forceinline__ int swz(int f) { return f + (f >> 4); }

__device__ __forceinline__ void fma_tap(float4 acc[TS], const float4* xw, int t,
                                        const float w[16]) {
#pragma unroll
    for (int j = 0; j < TS; ++j) {
        const float4 xv = xw[j + t];
        acc[j].x += xv.x*w[0] + xv.y*w[4] + xv.z*w[8]  + xv.w*w[12];
        acc[j].y += xv.x*w[1] + xv.y*w[5] + xv.z*w[9]  + xv.w*w[13];
        acc[j].z += xv.x*w[2] + xv.y*w[6] + xv.z*w[10] + xv.w*w[14];
        acc[j].w += xv.x*w[3] + xv.y*w[7] + xv.z*w[11] + xv.w*w[15];
    }
}

__global__ __launch_bounds__(256, 3)
void harmonic_conv_kernel(const float* __restrict__ x,
                          const float* __restrict__ W,
                          float* __restrict__ out) {
    __shared__ float4 lx[NROW * ROWP];   // 51 KB -> 3 blocks/CU

    const int bid  = blockIdx.x;
    const int work = ((bid & 7) << 8) | (bid >> 3);
    const int b    = work >> 9;
    const int s0   = (work & 511) * TS;
    const int tid  = threadIdx.x;

    const float4* xb = (const float4*)x + (size_t)b * SB * FB;
    float4*       ob = (float4*)out + (size_t)b * SB * FB;

#pragma unroll 1
    for (int rep = 0; rep < NREP; ++rep) {
        // ---- stage 6 rows x 512 f (coalesced); pad rows -> 0 ----
#pragma unroll
        for (int i = 0; i < NROW * FB / 256; ++i) {
            const int n  = i * 256 + tid;
            const int r  = n >> 9;
            const int f  = n & (FB - 1);
            const int sp = s0 + r - 2;
            float4 v = make_float4(0.f, 0.f, 0.f, 0.f);
            if (sp >= 0 && sp < SB) v = xb[(size_t)sp * FB + f];
            lx[r * ROWP + swz(f)] = v;
        }
        __syncthreads();

        // ---- hoist ALL unconditional gathers (18 ds_read_b128) ----
        const int gh = swz(tid + 256);
        const int g1 = swz(tid);
        const int g2 = swz(tid * 2);
        float4 xh[NROW], x1[NROW], x2[NROW];
#pragma unroll
        for (int r = 0; r < NROW; ++r) {
            xh[r] = lx[r * ROWP + gh];
            x1[r] = lx[r * ROWP + g1];
            x2[r] = lx[r * ROWP + g2];
        }

        float4 aH[TS], aL[TS];
#pragma unroll
        for (int j = 0; j < TS; ++j) {
            aH[j] = make_float4(0.f, 0.f, 0.f, 0.f);
            aL[j] = make_float4(0.f, 0.f, 0.f, 0.f);
        }

        // ---- fused tap loop: m=1 (high+low) + m=2 per SMEM wait ----
#pragma unroll
        for (int t = 0; t < NTAP; ++t) {
            const float* p1 = W + t * 64;
            const float* p2 = p1 + 16;
            float w1[16], w2[16];
#pragma unroll
            for (int i = 0; i < 16; ++i) { w1[i] = p1[i]; w2[i] = p2[i]; }
            fma_tap(aH, xh, t, w1);
            fma_tap(aL, x1, t, w1);
            fma_tap(aL, x2, t, w2);
        }
#pragma unroll
        for (int j = 0; j < TS; ++j)
            nt_store4(aH[j], &ob[(size_t)(s0 + j) * FB + (tid + 256)]);

        // ---- m=3 / m=4: wave-aligned branches, gathers hoisted ----
        if (tid * 3 < FB) {
            const int g3 = swz(tid * 3);
            float4 x3[NROW];
#pragma unroll
            for (int r = 0; r < NROW; ++r) x3[r] = lx[r * ROWP + g3];
            if (tid * 4 < FB) {
                const int g4 = swz(tid * 4);
                float4 x4[NROW];
#pragma unroll
                for (int r = 0; r < NROW; ++r) x4[r] = lx[r * ROWP + g4];
#pragma unroll
                for (int t = 0; t < NTAP; ++t) {
                    const float* p3 = W + t * 64 + 32;
                    const float* p4 = p3 + 16;
                    float w3[16], w4[16];
#pragma unroll
                    for (int i = 0; i < 16; ++i) { w3[i] = p3[i]; w4[i] = p4[i]; }
                    fma_tap(aL, x3, t, w3);
                    fma_tap(aL, x4, t, w4);
                }
            } else {
#pragma unroll
                for (int t = 0; t < NTAP; ++t) {
                    const float* p3 = W + t * 64 + 32;
                    float w3[16];
#pragma unroll
                    for (int i = 0; i < 16; ++i) w3[i] = p3[i];
                    fma_tap(aL, x3, t, w3);
                }
            }
        }
#pragma unroll
        for (int j = 0; j < TS; ++j)
            nt_store4(aL[j], &ob[(size_t)(s0 + j) * FB + tid]);

        // reps must not race and must not be elided
        __syncthreads();
        asm volatile("" ::: "memory");
    }
}

extern "C" void kernel_launch(void* const* d_in, const int* in_sizes, int n_in,
                              void* d_out, int out_size, void* d_ws, size_t ws_size,
                              hipStream_t stream) {
    const float* x = (const float*)d_in[0];
    const float* W = (const float*)d_in[1];
    float* out = (float*)d_out;
    const int nblocks = BB * (SB / TS);   // 2048
    harmonic_conv_kernel<<<nblocks, 256, 0, stream>>>(x, W, out);
}

// Round 14
// 96.266 us; speedup vs baseline: 1.6266x; 1.6266x over previous
//
#include <hip/hip_runtime.h>

// HarmonicConvolutionFilter on MI355X (round 14).
// x: [B=4, S=1024, F=512, C=4] f32;  W: [5, K=4, C=4, O=4] f32;  out: [B,S,F,4] f32
// out[b,s,f,o] = sum_t sum_k sum_c x_pad[b,s+t-2, f*(k+1), c] * W[t,k,c,o], k masked if f*(k+1)>=F
//
// Measurements: r10 (r6 body, NREP4): T=21.3us, VALUBusy 45.9%, FETCH 16.5MB
// (x L3-resident), conflicts 3.88M, occ 26.8%. r13 (r11 hoist+fuse body):
// T=28.7us REGRESSION -- weight hoisting blew SGPR budget (VGPR 68->84,
// VALU instrs +35%). Falsified "SMEM serialization"; we are ISSUE-BOUND:
// FMA 4.5us + ~5us VALU overhead + ~6us LDS pipe vs 21us wall, 3 waves/SIMD.
// Round-14 (r6 structure kept, weights JIT-loaded per harmonic):
//  1. v_pk_fma_f32 via ext_vector float2 (o-pairs, splat xv.c): FMA issue
//     slots halve (667 -> ~334/thread).
//  2. High half (f>=256, m=1, stride-1 window) reads GLOBAL direct, issued
//     before staging, consumed after sync: -6 ds_read/thread onto VMEM pipe.

#define TS    2
#define NTAP  5
#define FB    512
#define SB    1024
#define BB    4
#define NROW  (TS + 4)          // 6 rows
#define ROWP  544               // 512 + pad-per-16, float4 units

typedef float vfloat2 __attribute__((ext_vector_type(2)));
typedef float vfloat4 __attribute__((ext_vector_type(4)));

__device__ __forceinline__ void nt_store4(float4 v, float4* p) {
    vfloat4 raw = { v.x, v.y, v.z, v.w };
    __builtin_nontemporal_store(raw, (vfloat4*)p);
}

__device__ __forceinline__ int swz(int f) { return f + (f >> 4); }

// one tap, one 6-row window, packed o-pairs: 8 v_pk_fma_f32 per j-row
__device__ __forceinline__ void fma_tap_pk(vfloat2 a01[TS], vfloat2 a23[TS],
                                           const float4* xw, int t,
                                           const vfloat2 w[8]) {
#pragma unroll
    for (int j = 0; j < TS; ++j) {
        const float4 xv = xw[j + t];
        vfloat2 xx;
        xx = (vfloat2){xv.x, xv.x}; a01[j] += xx * w[0]; a23[j] += xx * w[1];
        xx = (vfloat2){xv.y, xv.y}; a01[j] += xx * w[2]; a23[j] += xx * w[3];
        xx = (vfloat2){xv.z, xv.z}; a01[j] += xx * w[4]; a23[j] += xx * w[5];
        xx = (vfloat2){xv.w, xv.w}; a01[j] += xx * w[6]; a23[j] += xx * w[7];
    }
}

// gather 6-row window for harmonic column g from LDS, run 5 taps
// Wk = W + (m-1)*16; weights JIT-loaded per tap (SGPR-friendly, r13 lesson)
__device__ __forceinline__ void accum_harm_pk(const float4* lx, int g,
                                              const float* __restrict__ Wk,
                                              vfloat2 a01[TS], vfloat2 a23[TS]) {
    float4 xw[NROW];
    const int gs = swz(g);
#pragma unroll
    for (int r = 0; r < NROW; ++r) xw[r] = lx[r * ROWP + gs];
#pragma unroll
    for (int t = 0; t < NTAP; ++t) {
        const vfloat2* wp = (const vfloat2*)(Wk + t * 64);  // uniform -> s_load
        vfloat2 w[8];
#pragma unroll
        for (int i = 0; i < 8; ++i) w[i] = wp[i];
        fma_tap_pk(a01, a23, xw, t, w);
    }
}

__global__ __launch_bounds__(256, 3)
void harmonic_conv_kernel(const float* __restrict__ x,
                          const float* __restrict__ W,
                          float* __restrict__ out) {
    __shared__ float4 lx[NROW * ROWP];   // 51 KB -> 3 blocks/CU

    // grid: BB * (SB/TS) = 2048 blocks of 256 threads
    const int bid  = blockIdx.x;
    const int work = ((bid & 7) << 8) | (bid >> 3);   // XCD-contiguous chunks
    const int b    = work >> 9;                       // 0..3
    const int s0   = (work & 511) * TS;               // 0..1022
    const int tid  = threadIdx.x;

    const float4* xb = (const float4*)x + (size_t)b * SB * FB;
    float4*       ob = (float4*)out + (size_t)b * SB * FB;

    // ---- high half (f = tid+256, m=1): global-direct, issued EARLY ----
    float4 xhg[NROW];
#pragma unroll
    for (int r = 0; r < NROW; ++r) {
        const int sp = s0 + r - 2;                    // block-uniform predicate
        xhg[r] = (sp >= 0 && sp < SB) ? xb[(size_t)sp * FB + (tid + 256)]
                                      : make_float4(0.f, 0.f, 0.f, 0.f);
    }

    // ---- stage 6 rows x 512 f into LDS (coalesced); pad rows -> 0 ----
#pragma unroll
    for (int i = 0; i < NROW * FB / 256; ++i) {       // 12 iters
        const int n  = i * 256 + tid;
        const int r  = n >> 9;
        const int f  = n & (FB - 1);
        const int sp = s0 + r - 2;
        float4 v = make_float4(0.f, 0.f, 0.f, 0.f);
        if (sp >= 0 && sp < SB) v = xb[(size_t)sp * FB + f];
        lx[r * ROWP + swz(f)] = v;
    }
    __syncthreads();

    vfloat2 a01[TS], a23[TS];

    // ---- high half compute (data already in registers) ----
#pragma unroll
    for (int j = 0; j < TS; ++j) { a01[j] = (vfloat2){0.f, 0.f}; a23[j] = (vfloat2){0.f, 0.f}; }
#pragma unroll
    for (int t = 0; t < NTAP; ++t) {
        const vfloat2* wp = (const vfloat2*)(W + t * 64);   // m=1 slice
        vfloat2 w[8];
#pragma unroll
        for (int i = 0; i < 8; ++i) w[i] = wp[i];
        fma_tap_pk(a01, a23, xhg, t, w);
    }
#pragma unroll
    for (int j = 0; j < TS; ++j)
        nt_store4(make_float4(a01[j].x, a01[j].y, a23[j].x, a23[j].y),
                  &ob[(size_t)(s0 + j) * FB + (tid + 256)]);

    // ---- low half: f = tid, harmonics m=1..4 from LDS ----
#pragma unroll
    for (int j = 0; j < TS; ++j) { a01[j] = (vfloat2){0.f, 0.f}; a23[j] = (vfloat2){0.f, 0.f}; }
    accum_harm_pk(lx, tid,     W,      a01, a23);             // m=1
    accum_harm_pk(lx, tid * 2, W + 16, a01, a23);             // m=2
    if (tid * 3 < FB) accum_harm_pk(lx, tid * 3, W + 32, a01, a23);   // m=3
    if (tid * 4 < FB) accum_harm_pk(lx, tid * 4, W + 48, a01, a23);   // m=4
#pragma unroll
    for (int j = 0; j < TS; ++j)
        nt_store4(make_float4(a01[j].x, a01[j].y, a23[j].x, a23[j].y),
                  &ob[(size_t)(s0 + j) * FB + tid]);
}

extern "C" void kernel_launch(void* const* d_in, const int* in_sizes, int n_in,
                              void* d_out, int out_size, void* d_ws, size_t ws_size,
                              hipStream_t stream) {
    const float* x = (const float*)d_in[0];
    const float* W = (const float*)d_in[1];
    float* out = (float*)d_out;
    const int nblocks = BB * (SB / TS);   // 2048
    harmonic_conv_kernel<<<nblocks, 256, 0, stream>>>(x, W, out);
}